// Round 10
// baseline (198.956 us; speedup 1.0000x reference)
//
#include <hip/hip_runtime.h>
#include <math.h>

// Problem dims
#define Bb 2
#define Tt 16
#define Hh 64
#define Ww 64
#define Cc 64
#define ST_ (Hh*Ww*Cc)    // 262144
#define SB_ (Tt*Hh*Ww*Cc) // 4194304

#define TWO_PI 6.2831853071795864769f

typedef __attribute__((ext_vector_type(8))) short bf16x8;
typedef __attribute__((ext_vector_type(4))) float f32x4;

// workspace u32-offsets: two ping-pong X buffers + tables
#define BUF_A    0u
#define BUF_B    8388608u
#define OFF_PRE  16777216u   // delta-W fragments            2048 u32
#define OFF_THF  16779264u   // fwd H (cpx K=128, re+im)     8192 u32
#define OFF_THI  16787456u   // inv H (cpx K=128, re+im,/64) 8192 u32
#define OFF_TWI  16795648u   // inv W (cpx K=128, re,/64)    4096 u32

__device__ __forceinline__ float2 cmul(float2 a, float2 b) {
    return make_float2(fmaf(a.x, b.x, -a.y * b.y), fmaf(a.x, b.y, a.y * b.x));
}
__device__ __forceinline__ float2 cadd(float2 a, float2 b) { return make_float2(a.x + b.x, a.y + b.y); }
__device__ __forceinline__ float2 csub(float2 a, float2 b) { return make_float2(a.x - b.x, a.y - b.y); }

// bf16 pair pack/unpack (x -> low 16, y -> high 16). RNE; range = fp32.
__device__ __forceinline__ unsigned bfpack(float2 f) {
    unsigned r = __float_as_uint(f.x);
    unsigned i = __float_as_uint(f.y);
    r = (r + 0x7fffu + ((r >> 16) & 1u)) >> 16;
    i = (i + 0x7fffu + ((i >> 16) & 1u)) >> 16;
    return r | (i << 16);
}
__device__ __forceinline__ float2 bfunpack(unsigned u) {
    return make_float2(__uint_as_float(u << 16), __uint_as_float(u & 0xffff0000u));
}

template <int S>
__device__ __forceinline__ void fft4(float2& a, float2& b, float2& c, float2& d) {
    float2 t0 = cadd(a, c), t1 = csub(a, c);
    float2 t2 = cadd(b, d), t3 = csub(b, d);
    a = cadd(t0, t2);
    c = csub(t0, t2);
    b = make_float2(t1.x - (float)S * t3.y, t1.y + (float)S * t3.x);
    d = make_float2(t1.x + (float)S * t3.y, t1.y - (float)S * t3.x);
}

// 16-pt FFT in registers, natural order in/out, radix 4x4.
template <int S>
__device__ __forceinline__ void fft16(float2 v[16]) {
    const float CS[10] = {1.f, 0.92387953f, 0.70710678f, 0.38268343f, 0.f,
                          -0.38268343f, -0.70710678f, -0.92387953f, -1.f, -0.92387953f};
    const float SN[10] = {0.f, 0.38268343f, 0.70710678f, 0.92387953f, 1.f,
                          0.92387953f, 0.70710678f, 0.38268343f, 0.f, -0.38268343f};
    float2 A[4][4];
#pragma unroll
    for (int j = 0; j < 4; ++j) {
        A[j][0] = v[j]; A[j][1] = v[4 + j]; A[j][2] = v[8 + j]; A[j][3] = v[12 + j];
        fft4<S>(A[j][0], A[j][1], A[j][2], A[j][3]);
#pragma unroll
        for (int k0 = 0; k0 < 4; ++k0) {
            int m = j * k0;
            float2 tw = make_float2(CS[m], (float)S * SN[m]);
            A[j][k0] = cmul(A[j][k0], tw);
        }
    }
#pragma unroll
    for (int k0 = 0; k0 < 4; ++k0) {
        fft4<S>(A[0][k0], A[1][k0], A[2][k0], A[3][k0]);
        v[k0] = A[0][k0]; v[k0 + 4] = A[1][k0]; v[k0 + 8] = A[2][k0]; v[k0 + 12] = A[3][k0];
    }
}

// ---------------------------------------------------------------------------
// Pass 1: MFMA DFT-64 along W. x (b,t,h,w,c) fp32 -> X1 (b,t,w,h,c) bf16 cpx.
// wg per (b,t,h). Twiddles self-computed (16 sincos/thread). Block 0 also
// builds the tables consumed by passes 2/3/4/5 (no race: consumed later).
// ---------------------------------------------------------------------------
__global__ __launch_bounds__(256) void k_dft_w_fwd(const float* __restrict__ x,
                                                   unsigned* __restrict__ X1,
                                                   const float* __restrict__ dW,
                                                   unsigned* __restrict__ ws) {
    __shared__ unsigned zs[64 * 68];   // staging (stride 66) then retile (stride 68)
    int tid = threadIdx.x;

    if (blockIdx.x == 0) {
        for (int j = tid; j < 22528; j += 256) {
            if (j < 2048) {
                int p2 = j & 3, lane = (j >> 2) & 63, ka = (j >> 8) & 1, nt = j >> 9;
                int kb = ka * 32 + (lane >> 4) * 8 + 2 * p2;
                int ccol = (lane & 15) + 16 * nt;
                ws[OFF_PRE + j] = bfpack(make_float2(dW[kb * 64 + ccol], dW[(kb + 1) * 64 + ccol]));
            } else {
                int idx, table;
                if (j < 10240)      { idx = j - 2048;  table = 1; }   // T_hf
                else if (j < 18432) { idx = j - 10240; table = 2; }   // T_hi
                else                { idx = j - 18432; table = 3; }   // T_wi
                int p = idx & 3;
                int lane = (idx >> 2) & 63;
                int m = lane & 15, q = lane >> 4;
                int ka, r, reim;
                if (table == 3) { ka = (idx >> 8) & 3; r = (idx >> 10) & 3; reim = 0; }
                else            { ka = (idx >> 8) & 3; r = (idx >> 10) & 3; reim = (idx >> 12) & 1; }
                int wp = r * 16 + m;
                int k0 = ka * 32 + q * 8 + 2 * p;
                float val[2];
#pragma unroll
                for (int dk = 0; dk < 2; ++dk) {
                    int k = k0 + dk;
                    int h = k >> 1;
                    int a = (wp * h) & 63;
                    float sn, cs; sincosf(TWO_PI * (float)a * (1.0f / 64.0f), &sn, &cs);
                    bool even = (k & 1) == 0;
                    float v;
                    if (table == 1) {
                        v = (reim == 0) ? (even ? cs : sn) : (even ? -sn : cs);
                    } else if (table == 2) {
                        v = ((reim == 0) ? (even ? cs : -sn) : (even ? sn : cs)) * (1.0f / 64.0f);
                    } else {
                        v = (even ? cs : -sn) * (1.0f / 64.0f);
                    }
                    val[dk] = v;
                }
                unsigned base = (table == 1) ? OFF_THF : (table == 2) ? OFF_THI : OFF_TWI;
                ws[base + idx] = bfpack(make_float2(val[0], val[1]));
            }
        }
    }

    int s = blockIdx.x;                // (b,t,h)
    const float4* src4 = (const float4*)(x + (size_t)s * 4096);
    // stage: pack (w even, w odd) bf16 pairs, c-major stride 66
#pragma unroll
    for (int k = 0; k < 2; ++k) {
        int idx = tid + k * 256;       // 0..511
        int i = idx >> 4, cc4 = idx & 15, c0 = cc4 * 4;
        float4 A = src4[(2 * i) * 16 + cc4];
        float4 B = src4[(2 * i + 1) * 16 + cc4];
        zs[(c0 + 0) * 66 + i] = bfpack(make_float2(A.x, B.x));
        zs[(c0 + 1) * 66 + i] = bfpack(make_float2(A.y, B.y));
        zs[(c0 + 2) * 66 + i] = bfpack(make_float2(A.z, B.z));
        zs[(c0 + 3) * 66 + i] = bfpack(make_float2(A.w, B.w));
    }
    __syncthreads();

    int r = tid >> 6, lane = tid & 63;
    int m = lane & 15, q = lane >> 4;
    int wp0 = r * 16 + m;
    union U48 { uint4 u4; uint2 u2[2]; unsigned u[4]; bf16x8 v8; };
    U48 Are[2], Aim[2], Bf;
    // self-computed twiddles: A[wp][k] = e^{-2pi i wp k/64}
#pragma unroll
    for (int ka = 0; ka < 2; ++ka) {
#pragma unroll
        for (int p = 0; p < 4; ++p) {
            float re[2], im[2];
#pragma unroll
            for (int dk = 0; dk < 2; ++dk) {
                int k = ka * 32 + q * 8 + 2 * p + dk;
                int a = (wp0 * k) & 63;
                float sn, cs; sincosf(TWO_PI * (float)a * (1.0f / 64.0f), &sn, &cs);
                re[dk] = cs; im[dk] = -sn;
            }
            Are[ka].u[p] = bfpack(make_float2(re[0], re[1]));
            Aim[ka].u[p] = bfpack(make_float2(im[0], im[1]));
        }
    }
    f32x4 ar[4], ai[4];
#pragma unroll
    for (int nt = 0; nt < 4; ++nt) { ar[nt] = (f32x4){0.f,0.f,0.f,0.f}; ai[nt] = (f32x4){0.f,0.f,0.f,0.f}; }
#pragma unroll
    for (int nt = 0; nt < 4; ++nt) {
        int cc = m + 16 * nt;
#pragma unroll
        for (int ka = 0; ka < 2; ++ka) {
            int i0 = ka * 16 + q * 4;
            Bf.u2[0] = *(const uint2*)&zs[cc * 66 + i0];
            Bf.u2[1] = *(const uint2*)&zs[cc * 66 + i0 + 2];
            ar[nt] = __builtin_amdgcn_mfma_f32_16x16x32_bf16(Are[ka].v8, Bf.v8, ar[nt], 0, 0, 0);
            ai[nt] = __builtin_amdgcn_mfma_f32_16x16x32_bf16(Aim[ka].v8, Bf.v8, ai[nt], 0, 0, 0);
        }
    }
    __syncthreads();
    // retile into [wp][cc] rows (stride 68, 2-way banks = free)
#pragma unroll
    for (int nt = 0; nt < 4; ++nt) {
        int cc = m + 16 * nt;
#pragma unroll
        for (int reg = 0; reg < 4; ++reg)
            zs[(r * 16 + q * 4 + reg) * 68 + cc] = bfpack(make_float2(ar[nt][reg], ai[nt][reg]));
    }
    __syncthreads();
    // vector stores: X1 (b,t,w',h,c), rows 256B at 16KB stride
    int bt = s >> 6, h = s & 63;
    unsigned* dst = X1 + (size_t)bt * 262144 + (size_t)h * 64;
#pragma unroll
    for (int rr = 0; rr < 4; ++rr) {
        int g = tid + 256 * rr;        // uint4 chunk 0..1023
        int row = g >> 4, c0 = (g & 15) * 4;
        *(uint4*)&dst[(size_t)row * 4096 + c0] = *(const uint4*)&zs[row * 68 + c0];
    }
}

// ---------------------------------------------------------------------------
// Complex MFMA DFT-64 pass (H axis), K=128 interleaved re/im. Reads contiguous
// slab, writes rotated rows. Template on output row stride.
// ---------------------------------------------------------------------------
template <int OSTRIDE>
__device__ __forceinline__ void dft_h_body(const unsigned* __restrict__ src,
                                           unsigned* __restrict__ dst,
                                           const uint4* __restrict__ T,
                                           unsigned* zs, int tid) {
    const uint4* src4 = (const uint4*)src;
#pragma unroll
    for (int k = 0; k < 4; ++k) {
        int idx4 = tid + k * 256;      // 0..1023
        uint4 d = src4[idx4];
        int i = idx4 * 4;
        int h = i >> 6, c0 = i & 63;
        zs[(c0 + 0) * 66 + h] = d.x;
        zs[(c0 + 1) * 66 + h] = d.y;
        zs[(c0 + 2) * 66 + h] = d.z;
        zs[(c0 + 3) * 66 + h] = d.w;
    }
    __syncthreads();

    int r = tid >> 6, lane = tid & 63;
    int m = lane & 15, q = lane >> 4;
    union U48 { uint4 u4; uint2 u2[2]; unsigned u[4]; bf16x8 v8; };
    U48 Are[4], Aim[4], Bf;
#pragma unroll
    for (int ka = 0; ka < 4; ++ka) {
        Are[ka].u4 = T[((0 * 4 + r) * 4 + ka) * 64 + lane];
        Aim[ka].u4 = T[((1 * 4 + r) * 4 + ka) * 64 + lane];
    }
    f32x4 ar[4], ai[4];
#pragma unroll
    for (int nt = 0; nt < 4; ++nt) { ar[nt] = (f32x4){0.f,0.f,0.f,0.f}; ai[nt] = (f32x4){0.f,0.f,0.f,0.f}; }
#pragma unroll
    for (int nt = 0; nt < 4; ++nt) {
        int cc = m + 16 * nt;
#pragma unroll
        for (int ka = 0; ka < 4; ++ka) {
            int h0 = ka * 16 + q * 4;
            Bf.u2[0] = *(const uint2*)&zs[cc * 66 + h0];
            Bf.u2[1] = *(const uint2*)&zs[cc * 66 + h0 + 2];
            ar[nt] = __builtin_amdgcn_mfma_f32_16x16x32_bf16(Are[ka].v8, Bf.v8, ar[nt], 0, 0, 0);
            ai[nt] = __builtin_amdgcn_mfma_f32_16x16x32_bf16(Aim[ka].v8, Bf.v8, ai[nt], 0, 0, 0);
        }
    }
    __syncthreads();
#pragma unroll
    for (int nt = 0; nt < 4; ++nt) {
        int cc = m + 16 * nt;
#pragma unroll
        for (int reg = 0; reg < 4; ++reg)
            zs[(r * 16 + q * 4 + reg) * 68 + cc] = bfpack(make_float2(ar[nt][reg], ai[nt][reg]));
    }
    __syncthreads();
#pragma unroll
    for (int rr = 0; rr < 4; ++rr) {
        int g = tid + 256 * rr;
        int row = g >> 4, c0 = (g & 15) * 4;
        *(uint4*)&dst[(size_t)row * OSTRIDE + c0] = *(const uint4*)&zs[row * 68 + c0];
    }
}

// Pass 2: X1 (b,t,w,h,c) -> X2 (b,h,w,t,c). wg per (b,t,w).
__global__ __launch_bounds__(256) void k_dft_h_fwd(const unsigned* __restrict__ X1,
                                                   unsigned* __restrict__ X2,
                                                   const uint4* __restrict__ T) {
    __shared__ unsigned zs[64 * 68];
    int s = blockIdx.x;
    int b = s >> 10, t = (s >> 6) & 15, w = s & 63;
    unsigned* dst = X2 + (size_t)b * 4194304 + (size_t)w * 1024 + (size_t)t * 64;
    dft_h_body<65536>(X1 + (size_t)s * 4096, dst, T, zs, threadIdx.x);
}

// Pass 4: X3 (b,t,w,h,c) -> X4 (b,t,h,w,c). wg per (b,t,w).
__global__ __launch_bounds__(256) void k_dft_h_inv(const unsigned* __restrict__ X3,
                                                   unsigned* __restrict__ X4,
                                                   const uint4* __restrict__ T) {
    __shared__ unsigned zs[64 * 68];
    int s = blockIdx.x;
    int bt = s >> 6, w = s & 63;
    unsigned* dst = X4 + (size_t)bt * 262144 + (size_t)w * 64;
    dft_h_body<4096>(X3 + (size_t)s * 4096, dst, T, zs, threadIdx.x);
}

// ---------------------------------------------------------------------------
// Pass 5: MFMA inverse DFT-64 along W, real out. X4 (b,t,h,w,c) slab ->
// out fp32 same layout (fully contiguous stores). wg per (b,t,h).
// ---------------------------------------------------------------------------
__global__ __launch_bounds__(256) void k_dft_w_inv(const unsigned* __restrict__ X4,
                                                   float* __restrict__ out,
                                                   const uint4* __restrict__ T) {
    __shared__ unsigned zs[64 * 68];
    int tid = threadIdx.x;
    int s = blockIdx.x;
    const uint4* src4 = (const uint4*)(X4 + (size_t)s * 4096);
#pragma unroll
    for (int k = 0; k < 4; ++k) {
        int idx4 = tid + k * 256;
        uint4 d = src4[idx4];
        int i = idx4 * 4;
        int w = i >> 6, c0 = i & 63;
        zs[(c0 + 0) * 66 + w] = d.x;
        zs[(c0 + 1) * 66 + w] = d.y;
        zs[(c0 + 2) * 66 + w] = d.z;
        zs[(c0 + 3) * 66 + w] = d.w;
    }
    __syncthreads();

    int r = tid >> 6, lane = tid & 63;
    int m = lane & 15, q = lane >> 4;
    union U48 { uint4 u4; uint2 u2[2]; unsigned u[4]; bf16x8 v8; };
    U48 Are[4], Bf;
#pragma unroll
    for (int ka = 0; ka < 4; ++ka)
        Are[ka].u4 = T[(r * 4 + ka) * 64 + lane];
    f32x4 ar[4];
#pragma unroll
    for (int nt = 0; nt < 4; ++nt) ar[nt] = (f32x4){0.f,0.f,0.f,0.f};
#pragma unroll
    for (int nt = 0; nt < 4; ++nt) {
        int cc = m + 16 * nt;
#pragma unroll
        for (int ka = 0; ka < 4; ++ka) {
            int w0 = ka * 16 + q * 4;
            Bf.u2[0] = *(const uint2*)&zs[cc * 66 + w0];
            Bf.u2[1] = *(const uint2*)&zs[cc * 66 + w0 + 2];
            ar[nt] = __builtin_amdgcn_mfma_f32_16x16x32_bf16(Are[ka].v8, Bf.v8, ar[nt], 0, 0, 0);
        }
    }
    __syncthreads();
    float* fz = (float*)zs;
#pragma unroll
    for (int nt = 0; nt < 4; ++nt) {
        int cc = m + 16 * nt;
#pragma unroll
        for (int reg = 0; reg < 4; ++reg)
            fz[(r * 16 + q * 4 + reg) * 68 + cc] = ar[nt][reg];
    }
    __syncthreads();
    float* dst = out + (size_t)s * 4096;
#pragma unroll
    for (int rr = 0; rr < 4; ++rr) {
        int g = tid + 256 * rr;
        int row = g >> 4, c0 = (g & 15) * 4;
        *(float4*)&dst[row * 64 + c0] = *(const float4*)&fz[row * 68 + c0];
    }
}

// ---------------------------------------------------------------------------
// k_mid: FFT-16 fwd along T + gates + MFMA delta-matmul + scan + FFT-16 inv.
// Reads X2 (b,h,w,t,c) (contiguous T-line) + x (scattered 256B rows, staged
// via float4+b128). Writes X3 (b,t,w,h,c). 4 waves = 4 sites. Scale 1/16.
// ---------------------------------------------------------------------------
__global__ __launch_bounds__(256) void k_mid(
    const float* __restrict__ x, const unsigned* __restrict__ X2,
    unsigned* __restrict__ X3,
    const float* __restrict__ Ak, const float* __restrict__ Bk,
    const float* __restrict__ fb, const float* __restrict__ fs,
    const float* __restrict__ ib, const float* __restrict__ isc_,
    const uint4* __restrict__ pre, const float* __restrict__ db) {
    const float CT[16] = {1.f, 0.9238795f, 0.7071068f, 0.3826834f, 0.f, -0.3826834f,
                          -0.7071068f, -0.9238795f, -1.f, -0.9238795f, -0.7071068f,
                          -0.3826834f, 0.f, 0.3826834f, 0.7071068f, 0.9238795f};
    const float SN[16] = {0.f, 0.3826834f, 0.7071068f, 0.9238795f, 1.f, 0.9238795f,
                          0.7071068f, 0.3826834f, 0.f, -0.3826834f, -0.7071068f,
                          -0.9238795f, -1.f, -0.9238795f, -0.7071068f, -0.3826834f};
    __shared__ float Akl[1728], Bkl[1728];
    __shared__ __align__(16) float xs[4][16 * 68];

    int tid = threadIdx.x;
    int g = tid >> 6, lane = tid & 63;
    int c = lane;
    int site = blockIdx.x * 4 + g;
    int b = site >> 12, hw = site & 4095;
    int h = hw >> 6, w = hw & 63;
    size_t base = (size_t)b * SB_ + (size_t)hw * 64;

    for (int i = tid; i < 432; i += 256) {
        *(float4*)&Akl[4 * i] = *(const float4*)&Ak[4 * i];
        *(float4*)&Bkl[4 * i] = *(const float4*)&Bk[4 * i];
    }

    // per-lane X2 T-line loads (contiguous 4KB/site, 256B per wave-instr)
    float2 v[16];
    const unsigned* src2 = X2 + (size_t)site * 1024;
#pragma unroll
    for (int t = 0; t < 16; ++t) v[t] = bfunpack(src2[t * 64 + c]);

    // wave-private x staging: float4 loads + b128 LDS writes
#pragma unroll
    for (int k = 0; k < 4; ++k) {
        int idx = lane + 64 * k;       // 0..255 float4 tasks for this site
        int t = idx >> 4, c0 = (idx & 15) * 4;
        float4 px = *(const float4*)&x[base + (size_t)t * ST_ + c0];
        *(float4*)&xs[g][t * 68 + c0] = px;
    }
    float xv[16];
#pragma unroll
    for (int t = 0; t < 16; ++t) xv[t] = xs[g][t * 68 + c];
    __syncthreads();   // Akl/Bkl visibility

    // MFMA delta matmul: D[t][ccol] = sum_d x[t][d] W[d][ccol] + db
    int m = lane & 15, q = lane >> 4;
    bf16x8 Afrag[2];
#pragma unroll
    for (int ka = 0; ka < 2; ++ka) {
        int d0 = ka * 32 + q * 8;
        const float* p = &xs[g][m * 68 + d0];
        float4 f0 = *(const float4*)p;
        float4 f1 = *(const float4*)(p + 4);
        union { bf16x8 v8; unsigned u[4]; } U;
        U.u[0] = bfpack(make_float2(f0.x, f0.y));
        U.u[1] = bfpack(make_float2(f0.z, f0.w));
        U.u[2] = bfpack(make_float2(f1.x, f1.y));
        U.u[3] = bfpack(make_float2(f1.z, f1.w));
        Afrag[ka] = U.v8;
    }
#pragma unroll
    for (int nt = 0; nt < 4; ++nt) {
        int ccol = m + 16 * nt;
        float dbn = db[ccol];
        f32x4 acc = {dbn, dbn, dbn, dbn};
#pragma unroll
        for (int ka = 0; ka < 2; ++ka) {
            union { bf16x8 v8; uint4 u4; } Ub;
            Ub.u4 = pre[(nt * 2 + ka) * 64 + lane];
            acc = __builtin_amdgcn_mfma_f32_16x16x32_bf16(Afrag[ka], Ub.v8, acc, 0, 0, 0);
        }
#pragma unroll
        for (int reg = 0; reg < 4; ++reg)
            xs[g][(q * 4 + reg) * 68 + ccol] = acc[reg];
    }

    // A_f/B_f generators from the 27 taps
    float sh, ch; sincosf(TWO_PI * (float)h / 64.0f, &sh, &ch);
    float sw, cw; sincosf(TWO_PI * (float)w / 64.0f, &sw, &cw);
    float2 eh[3] = { make_float2(ch, sh), make_float2(1.f, 0.f), make_float2(ch, -sh) };
    float2 ew[3] = { make_float2(cw, sw), make_float2(1.f, 0.f), make_float2(cw, -sw) };
    float2 GA[3], GB[3];
#pragma unroll
    for (int kt = 0; kt < 3; ++kt) { GA[kt] = make_float2(0.f, 0.f); GB[kt] = make_float2(0.f, 0.f); }
#pragma unroll
    for (int kh = 0; kh < 3; ++kh) {
#pragma unroll
        for (int kw = 0; kw < 3; ++kw) {
            float2 e = cmul(eh[kh], ew[kw]);
#pragma unroll
            for (int kt = 0; kt < 3; ++kt) {
                float ka = Akl[c * 27 + kt * 9 + kh * 3 + kw];
                float kb = Bkl[c * 27 + kt * 9 + kh * 3 + kw];
                GA[kt].x = fmaf(ka, e.x, GA[kt].x);
                GA[kt].y = fmaf(ka, e.y, GA[kt].y);
                GB[kt].x = fmaf(kb, e.x, GB[kt].x);
                GB[kt].y = fmaf(kb, e.y, GB[kt].y);
            }
        }
    }
    float fbc = fb[c], fsc = fs[c], ibc = ib[c], iscv = isc_[c];

    fft16<-1>(v);

    float delta_raw[16];
#pragma unroll
    for (int t = 0; t < 16; ++t) delta_raw[t] = xs[g][t * 68 + c];

    float2 hv = make_float2(0.f, 0.f);
#pragma unroll
    for (int t = 0; t < 16; ++t) {
        float ct = CT[t], st = SN[t];
        float2 Af, Bf;
        Af.x = GA[1].x + ct * (GA[0].x + GA[2].x) - st * (GA[0].y - GA[2].y);
        Af.y = GA[1].y + ct * (GA[0].y + GA[2].y) + st * (GA[0].x - GA[2].x);
        Bf.x = GB[1].x + ct * (GB[0].x + GB[2].x) - st * (GB[0].y - GB[2].y);
        Bf.y = GB[1].y + ct * (GB[0].y + GB[2].y) + st * (GB[0].x - GB[2].x);

        float xc = xv[t];
        float fg  = __builtin_amdgcn_rcpf(1.f + __expf(-(fbc + fsc * xc)));
        float igv = __builtin_amdgcn_rcpf(1.f + __expf(-(ibc + iscv * xc)));
        float dot = delta_raw[t];
        float delta = (dot > 20.f) ? dot : __logf(1.f + __expf(dot));

        float sR = igv * delta;
        float2 bbv;
        bbv.x = sR * (Bf.x * v[t].x - Bf.y * v[t].y);
        bbv.y = sR * (Bf.x * v[t].y + Bf.y * v[t].x);
        float2 av = make_float2(fg * Af.x, fg * Af.y);
        float2 nh;
        nh.x = av.x * hv.x - av.y * hv.y + bbv.x;
        nh.y = av.x * hv.y + av.y * hv.x + bbv.y;
        hv = nh;
        v[t] = hv;
    }

    fft16<1>(v);

    // write X3 (b,t,w,h,c): 256B rows per t (lane=c contiguous)
    size_t ob = (size_t)b * 4194304 + (size_t)w * 4096 + (size_t)h * 64 + c;
#pragma unroll
    for (int t = 0; t < 16; ++t) {
        float2 o = make_float2(v[t].x * 0.0625f, v[t].y * 0.0625f);
        X3[ob + (size_t)t * 262144] = bfpack(o);
    }
}

extern "C" void kernel_launch(void* const* d_in, const int* in_sizes, int n_in,
                              void* d_out, int out_size, void* d_ws, size_t ws_size,
                              hipStream_t stream) {
    const float* x   = (const float*)d_in[0];
    const float* Ak  = (const float*)d_in[1];
    const float* Bk  = (const float*)d_in[2];
    const float* fb  = (const float*)d_in[3];
    const float* fs  = (const float*)d_in[4];
    const float* ib  = (const float*)d_in[5];
    const float* is_ = (const float*)d_in[6];
    const float* dW  = (const float*)d_in[7];
    const float* db  = (const float*)d_in[8];
    float* out = (float*)d_out;
    unsigned* ws = (unsigned*)d_ws;
    unsigned* A = ws + BUF_A;
    unsigned* B = ws + BUF_B;

    k_dft_w_fwd<<<Bb * Tt * Hh, 256, 0, stream>>>(x, A, dW, ws);
    k_dft_h_fwd<<<Bb * Tt * Ww, 256, 0, stream>>>(A, B, (const uint4*)(ws + OFF_THF));
    k_mid<<<(Bb * Hh * Ww) / 4, 256, 0, stream>>>(x, B, A, Ak, Bk, fb, fs, ib, is_,
                                                  (const uint4*)(ws + OFF_PRE), db);
    k_dft_h_inv<<<Bb * Tt * Ww, 256, 0, stream>>>(A, B, (const uint4*)(ws + OFF_THI));
    k_dft_w_inv<<<Bb * Tt * Hh, 256, 0, stream>>>(B, out, (const uint4*)(ws + OFF_TWI));
}